// Round 8
// baseline (132.205 us; speedup 1.0000x reference)
//
#include <hip/hip_runtime.h>
#include <hip/hip_bf16.h>
#include <cstdint>

// EdgeMLP: score = W3 @ sig(W2 @ sig(W1 @ [h1_u,h1_v,h2_u,h2_u] + b1) + b2) + b3
// Factored: z1 = Anode[src] + Bnode[dst]  (A/B stored bf16, PERMUTED col order:
//   dword slot d of a row holds true cols (32*(d>>4) + (d&15), +16) as (lo,hi);
//   the permutation is compensated in W2F's k-index in prep).
// Node layer: bf16 MFMA, weight frags register-resident per wave n-quarter.
// Edge layer: BARRIER-FREE single-wave blocks — one wave owns 16 edges end-to-end,
//   full W2F in 128 VGPRs, private LDS patch for the A-frag transpose (in-order
//   per-wave LDS, no __syncthreads -> no vmcnt(0) drain; prefetch survives).

typedef __attribute__((ext_vector_type(8))) short bf16x8;
typedef __attribute__((ext_vector_type(4))) float f32x4;

__device__ __forceinline__ float sigmoid_fast(float x) {
    float e = __expf(-x);                       // v_mul + v_exp
    return __builtin_amdgcn_rcpf(1.0f + e);     // v_add + v_rcp  (~1 ulp)
}
__device__ __forceinline__ ushort f2bf_rne(float f) {      // prep path only
    uint32_t u = __float_as_uint(f);
    return (ushort)((u + 0x7fffu + ((u >> 16) & 1u)) >> 16);
}
__device__ __forceinline__ float bf2f_lo(uint32_t d) { return __uint_as_float(d << 16); }
__device__ __forceinline__ float bf2f_hi(uint32_t d) { return __uint_as_float(d & 0xffff0000u); }
__device__ __forceinline__ uint32_t packbf_rhu(float x, float y) {   // round-half-up
    return ((__float_as_uint(x) + 0x8000u) >> 16) |
           ((__float_as_uint(y) + 0x8000u) & 0xffff0000u);
}

// ---------- prep: weights -> bf16 MFMA B-fragment layouts ----------
// frag idx: ((kk*8+nt)*64+lane)*8 + j ; n = nt*16+(lane&15) ; kpos = kk*32+(lane>>4)*8+j
// WCF/WBF use true k = kpos. W2F uses permuted ktrue to match A/B dword packing.
__global__ void prep_kernel(const float* __restrict__ W1, const float* __restrict__ W2,
                            ushort* __restrict__ WCF, ushort* __restrict__ WBF,
                            ushort* __restrict__ W2F) {
    int i = blockIdx.x * blockDim.x + threadIdx.x;
    if (i >= 16384) return;
    int j = i & 7, lf = (i >> 3) & 63, nt = (i >> 9) & 7, kk = i >> 12;
    int n = nt * 16 + (lf & 15);
    int kpos = kk * 32 + ((lf >> 4) << 3) + j;
    int ktrue = (kpos & ~31) | ((kpos >> 1) & 15) | ((kpos & 1) << 4);
    W2F[i] = f2bf_rne(W2[n * 128 + ktrue]);
    float v = (kpos < 64) ? W1[n * 256 + kpos]
                          : W1[n * 256 + 128 + (kpos - 64)] + W1[n * 256 + 192 + (kpos - 64)];
    WCF[i] = f2bf_rne(v);
    if (kk < 2) WBF[i] = f2bf_rne(W1[n * 256 + 64 + kpos]);   // K=64: h1-half only
}

// ---------- node-side: MFMA, register weight frags, direct coalesced stores ----------
__global__ __launch_bounds__(256, 4) void node_kernel(
    const float* __restrict__ h1, const float* __restrict__ h2,
    const ushort* __restrict__ WCF, const ushort* __restrict__ WBF,
    const float* __restrict__ b1,
    uint32_t* __restrict__ Aout, uint32_t* __restrict__ Bout, int N)
{
    __shared__ __align__(16) ushort xt[64 * 136];   // [node][k true order]
    const int tid = threadIdx.x, g = tid >> 6, ln = tid & 63;
    const int nl = ln & 15, q = ln >> 4;
    const int n0 = blockIdx.x * 64;
    const bool full = (n0 + 64 <= N);

    // wave g owns n-cols [g*32, g*32+32): 12 weight frags -> 48 VGPRs
    bf16x8 fa[4][2], fb[2][2];
    #pragma unroll
    for (int kk = 0; kk < 4; ++kk)
        #pragma unroll
        for (int nt = 0; nt < 2; ++nt)
            fa[kk][nt] = *(const bf16x8*)(WCF + (((kk * 8 + g * 2 + nt) * 64 + ln) << 3));
    #pragma unroll
    for (int kk = 0; kk < 2; ++kk)
        #pragma unroll
        for (int nt = 0; nt < 2; ++nt)
            fb[kk][nt] = *(const bf16x8*)(WBF + (((kk * 8 + g * 2 + nt) * 64 + ln) << 3));
    const float b1c0 = b1[g * 32 + nl], b1c1 = b1[g * 32 + 16 + nl];

    // stage X = [h1|h2] as bf16 (true k order)
    #pragma unroll
    for (int i = 0; i < 8; ++i) {
        int local = i * 256 + tid;
        int node = local >> 5;
        int kq = (local & 31) * 4;
        float4 x = make_float4(0.f, 0.f, 0.f, 0.f);
        if (full || n0 + node < N)
            x = (kq < 64) ? *(const float4*)(h1 + (size_t)(n0 + node) * 64 + kq)
                          : *(const float4*)(h2 + (size_t)(n0 + node) * 64 + (kq - 64));
        uint32_t d0 = packbf_rhu(x.x, x.y), d1 = packbf_rhu(x.z, x.w);
        *(uint2*)&xt[node * 136 + kq] = make_uint2(d0, d1);
    }
    __syncthreads();

    #pragma unroll
    for (int m = 0; m < 4; ++m) {
        f32x4 accA[2], accB[2];
        #pragma unroll
        for (int r = 0; r < 4; ++r) { accA[0][r] = accA[1][r] = accB[0][r] = accB[1][r] = 0.f; }
        const ushort* arow = &xt[(m * 16 + nl) * 136 + (q << 3)];
        #pragma unroll
        for (int kk = 0; kk < 4; ++kk) {
            bf16x8 a = *(const bf16x8*)(arow + kk * 32);
            accA[0] = __builtin_amdgcn_mfma_f32_16x16x32_bf16(a, fa[kk][0], accA[0], 0, 0, 0);
            accA[1] = __builtin_amdgcn_mfma_f32_16x16x32_bf16(a, fa[kk][1], accA[1], 0, 0, 0);
            if (kk < 2) {
                accB[0] = __builtin_amdgcn_mfma_f32_16x16x32_bf16(a, fb[kk][0], accB[0], 0, 0, 0);
                accB[1] = __builtin_amdgcn_mfma_f32_16x16x32_bf16(a, fb[kk][1], accB[1], 0, 0, 0);
            }
        }
        // C/D: node = m*16 + q*4 + r, cols (g*32+nl, +16) -> dword slot g*16+nl
        #pragma unroll
        for (int r = 0; r < 4; ++r) {
            int node = n0 + m * 16 + q * 4 + r;
            if (full || node < N) {
                Aout[(size_t)node * 64 + g * 16 + nl] = packbf_rhu(accA[0][r] + b1c0, accA[1][r] + b1c1);
                Bout[(size_t)node * 64 + g * 16 + nl] = packbf_rhu(accB[0][r], accB[1][r]);
            }
        }
    }
}

// ---------- edge-side: barrier-free, one wave = 16 edges, full W2F in VGPRs ----------
__global__ __launch_bounds__(64, 2) void edge_kernel(
    const uint32_t* __restrict__ Am, const uint32_t* __restrict__ Bm,
    const int* __restrict__ src, const int* __restrict__ dst,
    const ushort* __restrict__ W2F, const float* __restrict__ b2,
    const float* __restrict__ W3, const float* __restrict__ b3,
    float* __restrict__ out, int E, int ngroups)
{
    __shared__ __align__(16) ushort hlds[16 * 136];   // 4352 B private patch
    const int ln = threadIdx.x;
    const int nl = ln & 15, q = ln >> 4;
    const int el = ln >> 2, p = ln & 3;               // gather: 4 lanes per edge

    // full W2 in registers: 32 B-frags = 128 VGPRs
    bf16x8 bfrag[32];
    #pragma unroll
    for (int kk = 0; kk < 4; ++kk)
        #pragma unroll
        for (int nt = 0; nt < 8; ++nt)
            bfrag[kk * 8 + nt] =
                *(const bf16x8*)(W2F + (((kk * 8 + nt) * 64 + ln) << 3));
    float b2c[8], w3c[8];
    #pragma unroll
    for (int nt = 0; nt < 8; ++nt) {
        b2c[nt] = b2[nt * 16 + nl];
        w3c[nt] = W3[nt * 16 + nl];
    }
    const float b3c = b3[0];

    uint4 ga[4], gb[4];
    int grp = blockIdx.x;
    if (grp < ngroups) {            // prologue: issue group-0 gather
        int eb = grp * 16, us = 0, vs = 0;
        if (ln < 16 && eb + ln < E) { us = src[eb + ln]; vs = dst[eb + ln]; }
        int uu = __shfl(us, el), vv = __shfl(vs, el);
        const uint32_t* ap = Am + (size_t)uu * 64 + p * 4;
        const uint32_t* bp = Bm + (size_t)vv * 64 + p * 4;
        #pragma unroll
        for (int r = 0; r < 4; ++r) {
            ga[r] = *(const uint4*)(ap + r * 16);
            gb[r] = *(const uint4*)(bp + r * 16);
        }
    }
    for (; grp < ngroups; grp += gridDim.x) {
        const int tn = grp + (int)gridDim.x;
        // issue next group's index loads (in flight through the commit phase)
        int us = 0, vs = 0;
        if (tn < ngroups) {
            int eb2 = tn * 16;
            if (ln < 16 && eb2 + ln < E) { us = src[eb2 + ln]; vs = dst[eb2 + ln]; }
        }

        // ---- commit current gather: sigmoid + pack -> private LDS ----
        #pragma unroll
        for (int r = 0; r < 4; ++r) {
            uint32_t sa[4] = {ga[r].x, ga[r].y, ga[r].z, ga[r].w};
            uint32_t sb[4] = {gb[r].x, gb[r].y, gb[r].z, gb[r].w};
            uint32_t da[4];
            #pragma unroll
            for (int d = 0; d < 4; ++d) {
                float zl = bf2f_lo(sa[d]) + bf2f_lo(sb[d]);
                float zh = bf2f_hi(sa[d]) + bf2f_hi(sb[d]);
                da[d] = packbf_rhu(sigmoid_fast(zl), sigmoid_fast(zh));
            }
            *(uint4*)&hlds[el * 136 + r * 32 + p * 8] =
                make_uint4(da[0], da[1], da[2], da[3]);
        }
        // ---- issue next group's row loads (in flight through MFMA phase) ----
        if (tn < ngroups) {
            int uu = __shfl(us, el), vv = __shfl(vs, el);
            const uint32_t* ap = Am + (size_t)uu * 64 + p * 4;
            const uint32_t* bp = Bm + (size_t)vv * 64 + p * 4;
            #pragma unroll
            for (int r = 0; r < 4; ++r) {
                ga[r] = *(const uint4*)(ap + r * 16);
                gb[r] = *(const uint4*)(bp + r * 16);
            }
        }

        // ---- A-frags from own LDS (in-order per-wave DS: no barrier needed) ----
        const ushort* arow = &hlds[nl * 136 + (q << 3)];
        bf16x8 a0 = *(const bf16x8*)(arow);
        bf16x8 a1 = *(const bf16x8*)(arow + 32);
        bf16x8 a2 = *(const bf16x8*)(arow + 64);
        bf16x8 a3 = *(const bf16x8*)(arow + 96);

        float pr[4] = {0.f, 0.f, 0.f, 0.f};
        #pragma unroll
        for (int np = 0; np < 4; ++np) {          // nt pairs for MFMA ILP
            const int n0t = 2 * np, n1t = 2 * np + 1;
            f32x4 acc0 = {0.f, 0.f, 0.f, 0.f}, acc1 = {0.f, 0.f, 0.f, 0.f};
            acc0 = __builtin_amdgcn_mfma_f32_16x16x32_bf16(a0, bfrag[n0t],      acc0, 0, 0, 0);
            acc1 = __builtin_amdgcn_mfma_f32_16x16x32_bf16(a0, bfrag[n1t],      acc1, 0, 0, 0);
            acc0 = __builtin_amdgcn_mfma_f32_16x16x32_bf16(a1, bfrag[8 + n0t],  acc0, 0, 0, 0);
            acc1 = __builtin_amdgcn_mfma_f32_16x16x32_bf16(a1, bfrag[8 + n1t],  acc1, 0, 0, 0);
            acc0 = __builtin_amdgcn_mfma_f32_16x16x32_bf16(a2, bfrag[16 + n0t], acc0, 0, 0, 0);
            acc1 = __builtin_amdgcn_mfma_f32_16x16x32_bf16(a2, bfrag[16 + n1t], acc1, 0, 0, 0);
            acc0 = __builtin_amdgcn_mfma_f32_16x16x32_bf16(a3, bfrag[24 + n0t], acc0, 0, 0, 0);
            acc1 = __builtin_amdgcn_mfma_f32_16x16x32_bf16(a3, bfrag[24 + n1t], acc1, 0, 0, 0);
            #pragma unroll
            for (int r = 0; r < 4; ++r) {
                pr[r] = fmaf(w3c[n0t], sigmoid_fast(acc0[r] + b2c[n0t]), pr[r]);
                pr[r] = fmaf(w3c[n1t], sigmoid_fast(acc1[r] + b2c[n1t]), pr[r]);
            }
        }
        #pragma unroll
        for (int r = 0; r < 4; ++r) {
            pr[r] += __shfl_xor(pr[r], 1, 16);
            pr[r] += __shfl_xor(pr[r], 2, 16);
            pr[r] += __shfl_xor(pr[r], 4, 16);
            pr[r] += __shfl_xor(pr[r], 8, 16);
        }
        if (nl == 0) {   // lanes 0,16,32,48 -> edges q*4..q*4+3 (C/D row = q*4+r)
            int eo = grp * 16 + q * 4;
            if (eo + 4 <= E) {
                *(float4*)(out + eo) = make_float4(pr[0] + b3c, pr[1] + b3c,
                                                   pr[2] + b3c, pr[3] + b3c);
            } else {
                #pragma unroll
                for (int r = 0; r < 4; ++r)
                    if (eo + r < E) out[eo + r] = pr[r] + b3c;
            }
        }
    }
}

// ---------- fallback (only if workspace too small) ----------
__global__ void naive_kernel(
    const float* __restrict__ h1, const float* __restrict__ h2,
    const int* __restrict__ src, const int* __restrict__ dst,
    const float* __restrict__ W1, const float* __restrict__ b1,
    const float* __restrict__ W2, const float* __restrict__ b2,
    const float* __restrict__ W3, const float* __restrict__ b3,
    float* __restrict__ out, int E, int N)
{
    int e = blockIdx.x * blockDim.x + threadIdx.x;
    if (e >= E) return;
    int u = src[e], v = dst[e];
    float h[128];
    for (int j = 0; j < 128; ++j) {
        float z = b1[j];
        const float* wj = W1 + j * 256;
        for (int k = 0; k < 64; ++k) {
            z += wj[k] * h1[(size_t)u * 64 + k]
               + wj[64 + k] * h1[(size_t)v * 64 + k]
               + (wj[128 + k] + wj[192 + k]) * h2[(size_t)u * 64 + k];
        }
        h[j] = 1.0f / (1.0f + __expf(-z));
    }
    float gg[128];
    for (int j = 0; j < 128; ++j) {
        float z = b2[j];
        for (int k = 0; k < 128; ++k) z = fmaf(W2[j * 128 + k], h[k], z);
        gg[j] = 1.0f / (1.0f + __expf(-z));
    }
    float s = b3[0];
    for (int j = 0; j < 128; ++j) s = fmaf(W3[j], gg[j], s);
    out[e] = s;
}

extern "C" void kernel_launch(void* const* d_in, const int* in_sizes, int n_in,
                              void* d_out, int out_size, void* d_ws, size_t ws_size,
                              hipStream_t stream) {
    const float* h1 = (const float*)d_in[0];
    const float* h2 = (const float*)d_in[1];
    const int*  src = (const int*)d_in[2];
    const int*  dst = (const int*)d_in[3];
    const float* W1 = (const float*)d_in[4];
    const float* b1 = (const float*)d_in[5];
    const float* W2 = (const float*)d_in[6];
    const float* b2 = (const float*)d_in[7];
    const float* W3 = (const float*)d_in[8];
    const float* b3 = (const float*)d_in[9];
    float* out = (float*)d_out;

    const int N = in_sizes[0] / 64;
    const int E = in_sizes[2];

    // workspace layout (float units)
    size_t offA   = 0;                         // N*64 dwords (bf16-pair packed)
    size_t offB   = offA + (size_t)N * 64;
    size_t offWCF = offB + (size_t)N * 64;     // 16384 ushorts
    size_t offWBF = offWCF + 8192;             // 8192 ushorts
    size_t offW2F = offWBF + 4096;             // 16384 ushorts
    size_t totalF = offW2F + 8192;

    if (ws_size < totalF * sizeof(float)) {
        naive_kernel<<<(E + 255) / 256, 256, 0, stream>>>(
            h1, h2, src, dst, W1, b1, W2, b2, W3, b3, out, E, N);
        return;
    }

    float* ws = (float*)d_ws;
    ushort* WCF = (ushort*)(ws + offWCF);
    ushort* WBF = (ushort*)(ws + offWBF);
    ushort* W2F = (ushort*)(ws + offW2F);

    prep_kernel<<<64, 256, 0, stream>>>(W1, W2, WCF, WBF, W2F);
    node_kernel<<<(N + 63) / 64, 256, 0, stream>>>(
        h1, h2, WCF, WBF, b1, (uint32_t*)(ws + offA), (uint32_t*)(ws + offB), N);
    const int ngroups = (E + 15) / 16;
    edge_kernel<<<2000, 64, 0, stream>>>(
        (const uint32_t*)(ws + offA), (const uint32_t*)(ws + offB), src, dst,
        W2F, b2, W3, b3, out, E, ngroups);
}